// Round 12
// baseline (1076.976 us; speedup 1.0000x reference)
//
#include <hip/hip_runtime.h>
#include <hip/hip_bf16.h>

typedef float f32x4 __attribute__((ext_vector_type(4)));
typedef __bf16 bf16_t;
typedef __bf16 bf16x4 __attribute__((ext_vector_type(4)));
typedef __bf16 bf16x8 __attribute__((ext_vector_type(8)));

#define MFMA16(a, b, c) __builtin_amdgcn_mfma_f32_16x16x32_bf16(a, b, c, 0, 0, 0)

constexpr int C_ = 128;
constexpr int N_ = 4096;
constexpr int M_ = 512;
constexpr int NL = 6;

#define NEG_INF (-__builtin_huge_valf())

// LDS strides: b128 reads want row-stride ≡ 4 mod 32 WORDS (uniform 8
// lane-words/bank). 136 bf16 = 68 words ≡ 4 ✓.  XC tile stride 40 bf16 =
// 80 B (16B-aligned rows for b128) = 20 words, same mult-of-4 bank family.
constexpr int XST = 136;   // xsT tile row stride (bf16)
constexpr int NSTP = 40;   // pool xs [c][n] apply tile row stride (bf16)

// ---------------------------------------------------------------------------
// Split fp32 array -> hi/lo bf16 (same layout). 1024 elems per block.
// ---------------------------------------------------------------------------
__global__ __launch_bounds__(256) void k_wsplit(const float* __restrict__ W,
                                                bf16_t* __restrict__ hi,
                                                bf16_t* __restrict__ lo) {
  const size_t i4 = ((size_t)blockIdx.x * 256 + threadIdx.x) * 4;
  f32x4 v = *(const f32x4*)&W[i4];
  bf16x4 h4, l4;
#pragma unroll
  for (int k = 0; k < 4; ++k) {
    bf16_t h = (bf16_t)v[k];
    h4[k] = h;
    l4[k] = (bf16_t)(v[k] - (float)h);
  }
  *(bf16x4*)&hi[i4] = h4;
  *(bf16x4*)&lo[i4] = l4;
}

// ---------------------------------------------------------------------------
// xs [b][c][n] fp32 -> xsThi/xsTlo [b][n][c] bf16 (transpose + split).
// ---------------------------------------------------------------------------
__global__ __launch_bounds__(256) void k_xsplit(const float* __restrict__ xs,
                                                bf16_t* __restrict__ thi,
                                                bf16_t* __restrict__ tlo) {
  __shared__ float T[128 * 68];  // [c][n]
  const int n0 = blockIdx.x * 64, b = blockIdx.y;
  const int t = threadIdx.x;
  const float* xsb = xs + (size_t)b * C_ * N_;
#pragma unroll
  for (int i = 0; i < 8; ++i) {
    int slot = i * 256 + t;  // 0..2047
    int c = slot >> 4, n4 = (slot & 15) * 4;
    *(f32x4*)&T[c * 68 + n4] = *(const f32x4*)&xsb[(size_t)c * N_ + n0 + n4];
  }
  __syncthreads();
  const int n = t >> 2, cb = (t & 3) * 32;
  bf16x8 h8[4], l8[4];
#pragma unroll
  for (int g = 0; g < 4; ++g)
#pragma unroll
    for (int j = 0; j < 8; ++j) {
      float v = T[(cb + g * 8 + j) * 68 + n];
      bf16_t hh = (bf16_t)v;
      h8[g][j] = hh;
      l8[g][j] = (bf16_t)(v - (float)hh);
    }
  const size_t base = ((size_t)b * N_ + n0 + n) * C_ + cb;
#pragma unroll
  for (int g = 0; g < 4; ++g) {
    *(bf16x8*)&thi[base + g * 8] = h8[g];
    *(bf16x8*)&tlo[base + g * 8] = l8[g];
  }
}

// ---------------------------------------------------------------------------
// Pool v9 (PASSED, 769us total): swapped-operand logits + in-reg P transpose
// + LDS-staged apply tile split on the fly from fp32 x.  Unchanged.
// ---------------------------------------------------------------------------
__global__ __launch_bounds__(256) void k_pool(const bf16_t* __restrict__ xsThi,
                                              const bf16_t* __restrict__ xsTlo,
                                              const float* __restrict__ x,
                                              const bf16_t* __restrict__ Wph,
                                              const bf16_t* __restrict__ Wpl,
                                              float* __restrict__ h_part,
                                              float* __restrict__ ml) {
  __shared__ bf16_t XH[32 * XST], XL[32 * XST];      // xsT [n][c] (logits)
  __shared__ bf16_t XCH[128 * NSTP], XCL[128 * NSTP]; // xs [c][n] (apply)
  const int d = blockIdx.x;
  const int lin = ((d & 7) << 7) | (d >> 3);
  const int b = lin >> 5, r5 = lin & 31;
  const int mt = r5 >> 2, seg = r5 & 3;
  const int m0 = mt * 64;
  const int t = threadIdx.x, w = t >> 6, lane = t & 63, l15 = lane & 15, q = lane >> 4;

  const int sn0 = t >> 4, sn1 = (256 + t) >> 4;
  const int scg = (t & 15) * 8;
  const size_t sgb = ((size_t)b * N_ + seg * 1024) * C_ + scg;
  const int xc = t >> 3, xn4 = (t & 7) * 4;
  const float* xb = x + (size_t)b * C_ * N_;

  bf16x8 aWh[4], aWl[4];
#pragma unroll
  for (int k = 0; k < 4; ++k) {
    const size_t ra = (size_t)(m0 + w * 16 + l15) * C_ + k * 32 + q * 8;
    aWh[k] = *(const bf16x8*)&Wph[ra];
    aWl[k] = *(const bf16x8*)&Wpl[ra];
  }

  f32x4 acc[8];
#pragma unroll
  for (int cs = 0; cs < 8; ++cs) acc[cs] = f32x4{0.f, 0.f, 0.f, 0.f};
  float lsum = 0.f;

  for (int ch = 0; ch < 32; ++ch) {
    const int n0g = seg * 1024 + ch * 32;
    const size_t off = sgb + (size_t)ch * 32 * C_;
    __syncthreads();
    bf16x8 th0 = *(const bf16x8*)&xsThi[off + (size_t)sn0 * C_];
    bf16x8 th1 = *(const bf16x8*)&xsThi[off + (size_t)sn1 * C_];
    bf16x8 tl0 = *(const bf16x8*)&xsTlo[off + (size_t)sn0 * C_];
    bf16x8 tl1 = *(const bf16x8*)&xsTlo[off + (size_t)sn1 * C_];
    f32x4 xv[4];
#pragma unroll
    for (int i = 0; i < 4; ++i) {
      const int c = xc + i * 32;
      xv[i] = *(const f32x4*)&xb[(size_t)c * N_ + n0g + xn4];
    }
    *(bf16x8*)&XH[sn0 * XST + scg] = th0;
    *(bf16x8*)&XH[sn1 * XST + scg] = th1;
    *(bf16x8*)&XL[sn0 * XST + scg] = tl0;
    *(bf16x8*)&XL[sn1 * XST + scg] = tl1;
#pragma unroll
    for (int i = 0; i < 4; ++i) {
      const int c = xc + i * 32;
      bf16x4 h4, l4;
#pragma unroll
      for (int j = 0; j < 4; ++j) {
        bf16_t hh = (bf16_t)xv[i][j];
        h4[j] = hh;
        l4[j] = (bf16_t)(xv[i][j] - (float)hh);
      }
      *(bf16x4*)&XCH[c * NSTP + xn4] = h4;
      *(bf16x4*)&XCL[c * NSTP + xn4] = l4;
    }
    __syncthreads();

    f32x4 U0 = f32x4{0.f, 0.f, 0.f, 0.f}, U1 = f32x4{0.f, 0.f, 0.f, 0.f};
#pragma unroll
    for (int k = 0; k < 4; ++k) {
      {
        const int o = l15 * XST + k * 32 + q * 8;
        bf16x8 bh = *(const bf16x8*)&XH[o];
        bf16x8 bl = *(const bf16x8*)&XL[o];
        U0 = MFMA16(bh, aWh[k], U0);
        U0 = MFMA16(bl, aWh[k], U0);
        U0 = MFMA16(bh, aWl[k], U0);
      }
      {
        const int o = (16 + l15) * XST + k * 32 + q * 8;
        bf16x8 bh = *(const bf16x8*)&XH[o];
        bf16x8 bl = *(const bf16x8*)&XL[o];
        U1 = MFMA16(bh, aWh[k], U1);
        U1 = MFMA16(bl, aWh[k], U1);
        U1 = MFMA16(bh, aWl[k], U1);
      }
    }

    f32x4 pe0, pe1;
#pragma unroll
    for (int r = 0; r < 4; ++r) {
      pe0[r] = __expf(U0[r]);
      pe1[r] = __expf(U1[r]);
      lsum += pe0[r] + pe1[r];
    }

    const int slo = l15 + ((lane & 16) ? 32 : 0);
    float pj[8];
#pragma unroll
    for (int r = 0; r < 4; ++r) {
      float a0 = __shfl(pe0[r], slo);
      float a1 = __shfl(pe1[r], slo);
      pj[r] = (q & 2) ? a1 : a0;
      float b0 = __shfl(pe0[r], slo + 16);
      float b1 = __shfl(pe1[r], slo + 16);
      pj[4 + r] = (q & 2) ? b1 : b0;
    }
    bf16x8 aPh, aPl;
#pragma unroll
    for (int j = 0; j < 8; ++j) {
      bf16_t hh = (bf16_t)pj[j];
      aPh[j] = hh;
      aPl[j] = (bf16_t)(pj[j] - (float)hh);
    }

#pragma unroll
    for (int cs = 0; cs < 8; ++cs) {
      const int ob = (cs * 16 + l15) * NSTP + q * 8;
      bf16x8 bh = *(const bf16x8*)&XCH[ob];
      bf16x8 bl = *(const bf16x8*)&XCL[ob];
      acc[cs] = MFMA16(aPh, bh, acc[cs]);
      acc[cs] = MFMA16(aPh, bl, acc[cs]);
      acc[cs] = MFMA16(aPl, bh, acc[cs]);
    }
  }

  const size_t sb = (size_t)seg * 32 + b;
  lsum += __shfl_xor(lsum, 16);
  lsum += __shfl_xor(lsum, 32);
  if (lane < 16) ml[sb * 512 + m0 + w * 16 + lane] = lsum;
#pragma unroll
  for (int cs = 0; cs < 8; ++cs)
#pragma unroll
    for (int r = 0; r < 4; ++r) {
      const int m = m0 + w * 16 + q * 4 + r;
      h_part[(sb * 512 + m) * 128 + cs * 16 + l15] = acc[cs][r];
    }
}

// ---------------------------------------------------------------------------
// Combine 4 n-segments: h[m][b*128+c].  (fixed max -> plain sums.)
// ---------------------------------------------------------------------------
__global__ __launch_bounds__(128) void k_combine(const float* __restrict__ h_part,
                                                 const float* __restrict__ ml,
                                                 float* __restrict__ hbuf) {
  const int mb = blockIdx.x;
  const int m = mb >> 5, b = mb & 31;
  const int c = threadIdx.x;
  float L = 0.f, acc = 0.f;
#pragma unroll
  for (int s = 0; s < 4; ++s) {
    L += ml[((size_t)s * 32 + b) * 512 + m];
    acc += h_part[(((size_t)s * 32 + b) * 512 + m) * 128 + c];
  }
  hbuf[(size_t)m * 4096 + b * 128 + c] = acc / L;
}

// ---------------------------------------------------------------------------
// h [512m][4096bc] fp32 -> hT hi/lo bf16 [4096bc][512m].  64x64 tiles.
// ---------------------------------------------------------------------------
__global__ __launch_bounds__(256) void k_hsplit(const float* __restrict__ h,
                                                bf16_t* __restrict__ thi,
                                                bf16_t* __restrict__ tlo) {
  __shared__ float T[64 * 65];  // [c][m]
  const int m0 = blockIdx.x * 64, c0 = blockIdx.y * 64;
  const int t = threadIdx.x;
#pragma unroll
  for (int ii = 0; ii < 4; ++ii) {
    int slot = ii * 256 + t;
    int m = slot >> 4, c4 = (slot & 15) * 4;
    f32x4 v = *(const f32x4*)&h[(size_t)(m0 + m) * 4096 + c0 + c4];
#pragma unroll
    for (int k = 0; k < 4; ++k) T[(c4 + k) * 65 + m] = v[k];
  }
  __syncthreads();
  const int row = t >> 2, mg = (t & 3) * 16;
  bf16x8 h8[2], l8[2];
#pragma unroll
  for (int half = 0; half < 2; ++half)
#pragma unroll
    for (int j = 0; j < 8; ++j) {
      float v = T[row * 65 + mg + half * 8 + j];
      bf16_t hh = (bf16_t)v;
      h8[half][j] = hh;
      l8[half][j] = (bf16_t)(v - (float)hh);
    }
  bf16_t* ph = &thi[(size_t)(c0 + row) * 512 + m0 + mg];
  bf16_t* pl = &tlo[(size_t)(c0 + row) * 512 + m0 + mg];
  *(bf16x8*)ph = h8[0];
  *(bf16x8*)(ph + 8) = h8[1];
  *(bf16x8*)pl = l8[0];
  *(bf16x8*)(pl + 8) = l8[1];
}

// ---------------------------------------------------------------------------
// Fused BN + residual + relu + transpose-split (validated ~+15us in v6).
// ---------------------------------------------------------------------------
__global__ __launch_bounds__(256) void k_bnsplit(const float* __restrict__ ybuf,
                                                 float* __restrict__ hbuf,
                                                 const float* __restrict__ stats,
                                                 const float* __restrict__ gamma,
                                                 const float* __restrict__ beta,
                                                 int l,
                                                 bf16_t* __restrict__ thi,
                                                 bf16_t* __restrict__ tlo) {
  __shared__ float T[64 * 65];  // [c][m]
  const int m0 = blockIdx.x * 64, c0 = blockIdx.y * 64;
  const int t = threadIdx.x;
#pragma unroll
  for (int ii = 0; ii < 4; ++ii) {
    int slot = ii * 256 + t;
    int m = slot >> 4, c4 = (slot & 15) * 4;
    const int o = m0 + m;
    const float mu = stats[l * 1024 + o] * (1.f / 4096.f);
    const float var = stats[l * 1024 + 512 + o] * (1.f / 4096.f) - mu * mu;
    const float rs = rsqrtf(var + 1e-5f);
    const float g = gamma[l * 512 + o];
    const float bt = beta[l * 512 + o];
    const size_t gidx = (size_t)o * 4096 + c0 + c4;
    f32x4 y = *(const f32x4*)&ybuf[gidx];
    f32x4 h = *(const f32x4*)&hbuf[gidx];
    f32x4 r;
#pragma unroll
    for (int k = 0; k < 4; ++k) {
      r[k] = fmaxf((y[k] - mu) * rs * g + bt + h[k], 0.f);
      T[(c4 + k) * 65 + m] = r[k];
    }
    *(f32x4*)&hbuf[gidx] = r;
  }
  __syncthreads();
  const int row = t >> 2, mg = (t & 3) * 16;
  bf16x8 h8[2], l8[2];
#pragma unroll
  for (int half = 0; half < 2; ++half)
#pragma unroll
    for (int j = 0; j < 8; ++j) {
      float v = T[row * 65 + mg + half * 8 + j];
      bf16_t hh = (bf16_t)v;
      h8[half][j] = hh;
      l8[half][j] = (bf16_t)(v - (float)hh);
    }
  bf16_t* ph = &thi[(size_t)(c0 + row) * 512 + m0 + mg];
  bf16_t* pl = &tlo[(size_t)(c0 + row) * 512 + m0 + mg];
  *(bf16x8*)ph = h8[0];
  *(bf16x8*)(ph + 8) = h8[1];
  *(bf16x8*)pl = l8[0];
  *(bf16x8*)(pl + 8) = l8[1];
}

// ---------------------------------------------------------------------------
// Layer GEMM via split-bf16 MFMA — unchanged.
// ---------------------------------------------------------------------------
__global__ __launch_bounds__(256) void k_layerA(const bf16_t* __restrict__ Whi,
                                                const bf16_t* __restrict__ Wlo,
                                                const bf16_t* __restrict__ hThi,
                                                const bf16_t* __restrict__ hTlo,
                                                int l, float* __restrict__ ybuf,
                                                float* __restrict__ stats) {
  const int o0 = blockIdx.x * 32;
  const int bc0 = blockIdx.y * 128;
  const int t = threadIdx.x;
  const int w = t >> 6, lane = t & 63, l15 = lane & 15, q = lane >> 4;
  const int bcw = bc0 + w * 32;
  const bf16_t* Wh = Whi + (size_t)l * M_ * M_;
  const bf16_t* Wl = Wlo + (size_t)l * M_ * M_;

  f32x4 acc[2][2];
#pragma unroll
  for (int i = 0; i < 2; ++i)
#pragma unroll
    for (int j = 0; j < 2; ++j) acc[i][j] = f32x4{0.f, 0.f, 0.f, 0.f};

  for (int k0 = 0; k0 < M_; k0 += 32) {
    bf16x8 ah[2], al[2], bh[2], bl[2];
#pragma unroll
    for (int os = 0; os < 2; ++os) {
      const size_t ro = (size_t)(o0 + os * 16 + l15) * M_ + k0 + q * 8;
      ah[os] = *(const bf16x8*)&Wh[ro];
      al[os] = *(const bf16x8*)&Wl[ro];
    }
#pragma unroll
    for (int ns = 0; ns < 2; ++ns) {
      const size_t rb = (size_t)(bcw + ns * 16 + l15) * M_ + k0 + q * 8;
      bh[ns] = *(const bf16x8*)&hThi[rb];
      bl[ns] = *(const bf16x8*)&hTlo[rb];
    }
#pragma unroll
    for (int os = 0; os < 2; ++os)
#pragma unroll
      for (int ns = 0; ns < 2; ++ns) {
        acc[os][ns] = MFMA16(ah[os], bh[ns], acc[os][ns]);
        acc[os][ns] = MFMA16(ah[os], bl[ns], acc[os][ns]);
        acc[os][ns] = MFMA16(al[os], bh[ns], acc[os][ns]);
      }
  }

  float s1[2][4], s2[2][4];
#pragma unroll
  for (int os = 0; os < 2; ++os)
#pragma unroll
    for (int r = 0; r < 4; ++r) {
      float a = 0.f, b2 = 0.f;
#pragma unroll
      for (int ns = 0; ns < 2; ++ns) {
        float v = acc[os][ns][r];
        ybuf[(size_t)(o0 + os * 16 + q * 4 + r) * 4096 + bcw + ns * 16 + l15] = v;
        a += v;
        b2 += v * v;
      }
      s1[os][r] = a;
      s2[os][r] = b2;
    }
#pragma unroll
  for (int os = 0; os < 2; ++os)
#pragma unroll
    for (int r = 0; r < 4; ++r) {
#pragma unroll
      for (int off = 1; off < 16; off <<= 1) {
        s1[os][r] += __shfl_xor(s1[os][r], off);
        s2[os][r] += __shfl_xor(s2[os][r], off);
      }
      if (l15 == 0) {
        const int o = o0 + os * 16 + q * 4 + r;
        atomicAdd(&stats[l * 1024 + o], s1[os][r]);
        atomicAdd(&stats[l * 1024 + 512 + o], s2[os][r]);
      }
    }
}

// ---------------------------------------------------------------------------
// Unpool v5: wave-owns-n restructure.  Wave w owns columns n = w*16+l15 for
// the whole block; softmax-over-m is wave-local (colsum in regs, reduced
// once at end); P stays in registers via the v8-verified shfl-transpose
// (sources pe[2ks]/pe[2ks+1], select by target q&2); xsT B-frags preloaded
// from LDS once per block.  ZERO barriers and zero LDS traffic in the
// m-loop; PH/PL + colsum/L/alpha LDS deleted (54.8 -> 34.8 KB).
// ---------------------------------------------------------------------------
__global__ __launch_bounds__(256) void k_unpool(const bf16_t* __restrict__ xsThi,
                                                const bf16_t* __restrict__ xsTlo,
                                                const bf16_t* __restrict__ Wuh,
                                                const bf16_t* __restrict__ Wul,
                                                const float* __restrict__ bun,
                                                const bf16_t* __restrict__ x1hi,
                                                const bf16_t* __restrict__ x1lo,
                                                float* __restrict__ out) {
  __shared__ bf16_t XH[64 * XST], XL[64 * XST];
  const int n0 = blockIdx.x * 64, b = blockIdx.y;
  const int t = threadIdx.x, w = t >> 6, lane = t & 63, l15 = lane & 15, q = lane >> 4;

  // stage xsT tile [64n][128c] (coalesced, once)
#pragma unroll
  for (int i = 0; i < 4; ++i) {
    int slot = i * 256 + t;
    int n = slot >> 4, cg = (slot & 15) * 8;
    const size_t g = ((size_t)b * N_ + n0 + n) * C_ + cg;
    *(bf16x8*)&XH[n * XST + cg] = *(const bf16x8*)&xsThi[g];
    *(bf16x8*)&XL[n * XST + cg] = *(const bf16x8*)&xsTlo[g];
  }
  __syncthreads();

  // preload xsT B-frags for this wave's n = n0 + w*16 + l15 (fixed all block)
  bf16x8 bXh[4], bXl[4];
#pragma unroll
  for (int k = 0; k < 4; ++k) {
    const int o = (w * 16 + l15) * XST + k * 32 + q * 8;
    bXh[k] = *(const bf16x8*)&XH[o];
    bXl[k] = *(const bf16x8*)&XL[o];
  }

  f32x4 acc[8];
#pragma unroll
  for (int cs = 0; cs < 8; ++cs) acc[cs] = f32x4{0.f, 0.f, 0.f, 0.f};
  float lsum = 0.f;  // partial colsum for n = n0 + w*16 + l15

  for (int ch = 0; ch < 8; ++ch) {
    const int mg0 = ch * 64;
    // ---- logits U[64m][16n] for this wave's n-frag ----
    f32x4 U[4];
#pragma unroll
    for (int mt = 0; mt < 4; ++mt) U[mt] = f32x4{0.f, 0.f, 0.f, 0.f};
#pragma unroll
    for (int k = 0; k < 4; ++k) {
#pragma unroll
      for (int mt = 0; mt < 4; ++mt) {
        const size_t ra = (size_t)(mg0 + mt * 16 + l15) * C_ + k * 32 + q * 8;
        bf16x8 ah = *(const bf16x8*)&Wuh[ra];
        bf16x8 al = *(const bf16x8*)&Wul[ra];
        U[mt] = MFMA16(ah, bXh[k], U[mt]);
        U[mt] = MFMA16(ah, bXl[k], U[mt]);
        U[mt] = MFMA16(al, bXh[k], U[mt]);
      }
    }

    // ---- p = exp(U + bias); per-lane colsum partial (no LDS) ----
    f32x4 pe[4];
#pragma unroll
    for (int mt = 0; mt < 4; ++mt) {
      f32x4 bi = *(const f32x4*)&bun[mg0 + mt * 16 + q * 4];
#pragma unroll
      for (int r = 0; r < 4; ++r) {
        float pv = __expf(U[mt][r] + bi[r]);
        pe[mt][r] = pv;
        lsum += pv;
      }
    }

    // ---- apply: out[c][n] += x1[c][m] * P[m][n]; P B-frag via in-reg
    // transpose (v8 pattern): lane (l15,q) needs P[m=ks*32+q*8+j][n=l15].
    const int slo = l15 + ((lane & 16) ? 32 : 0);
#pragma unroll
    for (int ks = 0; ks < 2; ++ks) {
      float pj[8];
#pragma unroll
      for (int r = 0; r < 4; ++r) {
        float a0 = __shfl(pe[2 * ks][r], slo);
        float a1 = __shfl(pe[2 * ks + 1][r], slo);
        pj[r] = (q & 2) ? a1 : a0;
        float b0 = __shfl(pe[2 * ks][r], slo + 16);
        float b1 = __shfl(pe[2 * ks + 1][r], slo + 16);
        pj[4 + r] = (q & 2) ? b1 : b0;
      }
      bf16x8 bPh, bPl;
#pragma unroll
      for (int j = 0; j < 8; ++j) {
        bf16_t hh = (bf16_t)pj[j];
        bPh[j] = hh;
        bPl[j] = (bf16_t)(pj[j] - (float)hh);
      }
#pragma unroll
      for (int cs = 0; cs < 8; ++cs) {
        const size_t ga =
            ((size_t)b * 128 + cs * 16 + l15) * M_ + mg0 + ks * 32 + q * 8;
        bf16x8 ah = *(const bf16x8*)&x1hi[ga];
        bf16x8 al = *(const bf16x8*)&x1lo[ga];
        acc[cs] = MFMA16(ah, bPh, acc[cs]);
        acc[cs] = MFMA16(ah, bPl, acc[cs]);
        acc[cs] = MFMA16(al, bPh, acc[cs]);
      }
    }
  }

  // colsum over all m: reduce across the 4 q-lane groups
  lsum += __shfl_xor(lsum, 16);
  lsum += __shfl_xor(lsum, 32);
  const float invL = 1.f / lsum;

#pragma unroll
  for (int cs = 0; cs < 8; ++cs) {
#pragma unroll
    for (int r = 0; r < 4; ++r) {
      const int c = cs * 16 + q * 4 + r;
      out[((size_t)b * 128 + c) * (size_t)N_ + n0 + w * 16 + l15] =
          acc[cs][r] * invL;
    }
  }
}

// ---------------------------------------------------------------------------
extern "C" void kernel_launch(void* const* d_in, const int* in_sizes, int n_in,
                              void* d_out, int out_size, void* d_ws, size_t ws_size,
                              hipStream_t stream) {
  const float* x = (const float*)d_in[0];
  const float* W_pool = (const float*)d_in[1];
  const float* Wf = (const float*)d_in[2];
  const float* gamma = (const float*)d_in[3];
  const float* beta = (const float*)d_in[4];
  const float* W_unpool = (const float*)d_in[5];
  const float* b_unpool = (const float*)d_in[6];
  float* out = (float*)d_out;

  char* ws = (char*)d_ws;
  float* h_part = (float*)ws; ws += (size_t)4 * 32 * 512 * 128 * 4;  // 33.55 MB
  float* ml = (float*)ws;     ws += (size_t)4 * 32 * 512 * 4;        // 0.26 MB
  float* hbuf = (float*)ws;   ws += (size_t)512 * 4096 * 4;          // 8.39 MB
  float* stats = (float*)ws;  ws += NL * 1024 * 4;
  bf16_t* xsThi = (bf16_t*)ws; ws += (size_t)32 * N_ * C_ * 2;       // 33.55 MB
  bf16_t* xsTlo = (bf16_t*)ws; ws += (size_t)32 * N_ * C_ * 2;       // 33.55 MB
  bf16_t* Wuh = (bf16_t*)ws;  ws += (size_t)M_ * C_ * 2;
  bf16_t* Wul = (bf16_t*)ws;  ws += (size_t)M_ * C_ * 2;
  bf16_t* Wph = (bf16_t*)ws;  ws += (size_t)M_ * C_ * 2;
  bf16_t* Wpl = (bf16_t*)ws;  ws += (size_t)M_ * C_ * 2;
  bf16_t* Whi = (bf16_t*)ws;  ws += (size_t)NL * M_ * M_ * 2;        // 3.15 MB
  bf16_t* Wlo = (bf16_t*)ws;  ws += (size_t)NL * M_ * M_ * 2;        // 3.15 MB
  // aliased into h_part (dead after k_combine):
  char* hp = (char*)h_part;
  float* ybuf = (float*)(hp);                  // 8.39 MB
  bf16_t* hThi = (bf16_t*)(hp + 8388608);      // 4.19 MB
  bf16_t* hTlo = (bf16_t*)(hp + 12582912);     // 4.19 MB

  hipMemsetAsync(stats, 0, NL * 1024 * 4, stream);
  k_xsplit<<<dim3(64, 32), 256, 0, stream>>>(x, xsThi, xsTlo);
  k_wsplit<<<dim3(64), 256, 0, stream>>>(W_pool, Wph, Wpl);
  k_wsplit<<<dim3(64), 256, 0, stream>>>(W_unpool, Wuh, Wul);
  k_wsplit<<<dim3(1536), 256, 0, stream>>>(Wf, Whi, Wlo);
  k_pool<<<dim3(1024), 256, 0, stream>>>(xsThi, xsTlo, x, Wph, Wpl,
                                         h_part, ml);
  k_combine<<<dim3(16384), 128, 0, stream>>>(h_part, ml, hbuf);
  k_hsplit<<<dim3(8, 64), 256, 0, stream>>>(hbuf, hThi, hTlo);
  for (int l = 0; l < NL; ++l) {
    k_layerA<<<dim3(16, 32), 256, 0, stream>>>(Whi, Wlo, hThi, hTlo, l, ybuf, stats);
    k_bnsplit<<<dim3(8, 64), 256, 0, stream>>>(ybuf, hbuf, stats, gamma, beta, l,
                                               hThi, hTlo);
  }
  k_unpool<<<dim3(64, 32), 256, 0, stream>>>(xsThi, xsTlo, Wuh, Wul, b_unpool,
                                             hThi, hTlo, out);
}

// Round 13
// 700.245 us; speedup vs baseline: 1.5380x; 1.5380x over previous
//
#include <hip/hip_runtime.h>
#include <hip/hip_bf16.h>

typedef float f32x4 __attribute__((ext_vector_type(4)));
typedef __bf16 bf16_t;
typedef __bf16 bf16x4 __attribute__((ext_vector_type(4)));
typedef __bf16 bf16x8 __attribute__((ext_vector_type(8)));

#define MFMA16(a, b, c) __builtin_amdgcn_mfma_f32_16x16x32_bf16(a, b, c, 0, 0, 0)

constexpr int C_ = 128;
constexpr int N_ = 4096;
constexpr int M_ = 512;
constexpr int NL = 6;

#define NEG_INF (-__builtin_huge_valf())

constexpr int XST = 136;   // xsT tile row stride (bf16), 68 words ≡ 4 mod 32
constexpr int NSTP = 40;   // pool xs [c][n] apply tile row stride (bf16)
constexpr int PSTU = 72;   // unpool P row stride (bf16)

// ---------------------------------------------------------------------------
// Split fp32 array -> hi/lo bf16 (same layout). 1024 elems per block.
// (used for W_pool only now)
// ---------------------------------------------------------------------------
__global__ __launch_bounds__(256) void k_wsplit(const float* __restrict__ W,
                                                bf16_t* __restrict__ hi,
                                                bf16_t* __restrict__ lo) {
  const size_t i4 = ((size_t)blockIdx.x * 256 + threadIdx.x) * 4;
  f32x4 v = *(const f32x4*)&W[i4];
  bf16x4 h4, l4;
#pragma unroll
  for (int k = 0; k < 4; ++k) {
    bf16_t h = (bf16_t)v[k];
    h4[k] = h;
    l4[k] = (bf16_t)(v[k] - (float)h);
  }
  *(bf16x4*)&hi[i4] = h4;
  *(bf16x4*)&lo[i4] = l4;
}

// ---------------------------------------------------------------------------
// Wf [l][o][m] fp32 -> blocked hi/lo: addr = ((l*16 + m/32)*512 + o)*32 + m%32
// (MFMA A-frag for layerA: lane reads contiguous 1KB)
// ---------------------------------------------------------------------------
__global__ __launch_bounds__(256) void k_wfsplit(const float* __restrict__ W,
                                                 bf16_t* __restrict__ hi,
                                                 bf16_t* __restrict__ lo) {
  const size_t i4 = ((size_t)blockIdx.x * 256 + threadIdx.x) * 4;
  const int l = (int)(i4 >> 18);            // /(512*512)
  const int rem = (int)(i4 & 262143);
  const int o = rem >> 9, m = rem & 511;    // m multiple of 4
  f32x4 v = *(const f32x4*)&W[i4];
  bf16x4 h4, l4;
#pragma unroll
  for (int k = 0; k < 4; ++k) {
    bf16_t h = (bf16_t)v[k];
    h4[k] = h;
    l4[k] = (bf16_t)(v[k] - (float)h);
  }
  const size_t ad = (((size_t)l * 16 + (m >> 5)) * 512 + o) * 32 + (m & 31);
  *(bf16x4*)&hi[ad] = h4;
  *(bf16x4*)&lo[ad] = l4;
}

// ---------------------------------------------------------------------------
// Wu [m][c] fp32 -> blocked hi/lo: addr = ((c/32)*512 + m)*32 + c%32
// (MFMA A-frag for unpool logits: lane reads contiguous 1KB)
// ---------------------------------------------------------------------------
__global__ __launch_bounds__(256) void k_wusplit(const float* __restrict__ W,
                                                 bf16_t* __restrict__ hi,
                                                 bf16_t* __restrict__ lo) {
  const size_t i4 = ((size_t)blockIdx.x * 256 + threadIdx.x) * 4;
  const int m = (int)(i4 >> 7), c = (int)(i4 & 127);  // c multiple of 4
  f32x4 v = *(const f32x4*)&W[i4];
  bf16x4 h4, l4;
#pragma unroll
  for (int k = 0; k < 4; ++k) {
    bf16_t h = (bf16_t)v[k];
    h4[k] = h;
    l4[k] = (bf16_t)(v[k] - (float)h);
  }
  const size_t ad = ((size_t)(c >> 5) * 512 + m) * 32 + (c & 31);
  *(bf16x4*)&hi[ad] = h4;
  *(bf16x4*)&lo[ad] = l4;
}

// ---------------------------------------------------------------------------
// xs [b][c][n] fp32 -> xsThi/xsTlo [b][n][c] bf16 (transpose + split).
// ---------------------------------------------------------------------------
__global__ __launch_bounds__(256) void k_xsplit(const float* __restrict__ xs,
                                                bf16_t* __restrict__ thi,
                                                bf16_t* __restrict__ tlo) {
  __shared__ float T[128 * 68];  // [c][n]
  const int n0 = blockIdx.x * 64, b = blockIdx.y;
  const int t = threadIdx.x;
  const float* xsb = xs + (size_t)b * C_ * N_;
#pragma unroll
  for (int i = 0; i < 8; ++i) {
    int slot = i * 256 + t;  // 0..2047
    int c = slot >> 4, n4 = (slot & 15) * 4;
    *(f32x4*)&T[c * 68 + n4] = *(const f32x4*)&xsb[(size_t)c * N_ + n0 + n4];
  }
  __syncthreads();
  const int n = t >> 2, cb = (t & 3) * 32;
  bf16x8 h8[4], l8[4];
#pragma unroll
  for (int g = 0; g < 4; ++g)
#pragma unroll
    for (int j = 0; j < 8; ++j) {
      float v = T[(cb + g * 8 + j) * 68 + n];
      bf16_t hh = (bf16_t)v;
      h8[g][j] = hh;
      l8[g][j] = (bf16_t)(v - (float)hh);
    }
  const size_t base = ((size_t)b * N_ + n0 + n) * C_ + cb;
#pragma unroll
  for (int g = 0; g < 4; ++g) {
    *(bf16x8*)&thi[base + g * 8] = h8[g];
    *(bf16x8*)&tlo[base + g * 8] = l8[g];
  }
}

// ---------------------------------------------------------------------------
// Pool v9 (measured: total 769us, k_pool off top-5): unchanged.
// ---------------------------------------------------------------------------
__global__ __launch_bounds__(256) void k_pool(const bf16_t* __restrict__ xsThi,
                                              const bf16_t* __restrict__ xsTlo,
                                              const float* __restrict__ x,
                                              const bf16_t* __restrict__ Wph,
                                              const bf16_t* __restrict__ Wpl,
                                              float* __restrict__ h_part,
                                              float* __restrict__ ml) {
  __shared__ bf16_t XH[32 * XST], XL[32 * XST];
  __shared__ bf16_t XCH[128 * NSTP], XCL[128 * NSTP];
  const int d = blockIdx.x;
  const int lin = ((d & 7) << 7) | (d >> 3);
  const int b = lin >> 5, r5 = lin & 31;
  const int mt = r5 >> 2, seg = r5 & 3;
  const int m0 = mt * 64;
  const int t = threadIdx.x, w = t >> 6, lane = t & 63, l15 = lane & 15, q = lane >> 4;

  const int sn0 = t >> 4, sn1 = (256 + t) >> 4;
  const int scg = (t & 15) * 8;
  const size_t sgb = ((size_t)b * N_ + seg * 1024) * C_ + scg;
  const int xc = t >> 3, xn4 = (t & 7) * 4;
  const float* xb = x + (size_t)b * C_ * N_;

  bf16x8 aWh[4], aWl[4];
#pragma unroll
  for (int k = 0; k < 4; ++k) {
    const size_t ra = (size_t)(m0 + w * 16 + l15) * C_ + k * 32 + q * 8;
    aWh[k] = *(const bf16x8*)&Wph[ra];
    aWl[k] = *(const bf16x8*)&Wpl[ra];
  }

  f32x4 acc[8];
#pragma unroll
  for (int cs = 0; cs < 8; ++cs) acc[cs] = f32x4{0.f, 0.f, 0.f, 0.f};
  float lsum = 0.f;

  for (int ch = 0; ch < 32; ++ch) {
    const int n0g = seg * 1024 + ch * 32;
    const size_t off = sgb + (size_t)ch * 32 * C_;
    __syncthreads();
    bf16x8 th0 = *(const bf16x8*)&xsThi[off + (size_t)sn0 * C_];
    bf16x8 th1 = *(const bf16x8*)&xsThi[off + (size_t)sn1 * C_];
    bf16x8 tl0 = *(const bf16x8*)&xsTlo[off + (size_t)sn0 * C_];
    bf16x8 tl1 = *(const bf16x8*)&xsTlo[off + (size_t)sn1 * C_];
    f32x4 xv[4];
#pragma unroll
    for (int i = 0; i < 4; ++i) {
      const int c = xc + i * 32;
      xv[i] = *(const f32x4*)&xb[(size_t)c * N_ + n0g + xn4];
    }
    *(bf16x8*)&XH[sn0 * XST + scg] = th0;
    *(bf16x8*)&XH[sn1 * XST + scg] = th1;
    *(bf16x8*)&XL[sn0 * XST + scg] = tl0;
    *(bf16x8*)&XL[sn1 * XST + scg] = tl1;
#pragma unroll
    for (int i = 0; i < 4; ++i) {
      const int c = xc + i * 32;
      bf16x4 h4, l4;
#pragma unroll
      for (int j = 0; j < 4; ++j) {
        bf16_t hh = (bf16_t)xv[i][j];
        h4[j] = hh;
        l4[j] = (bf16_t)(xv[i][j] - (float)hh);
      }
      *(bf16x4*)&XCH[c * NSTP + xn4] = h4;
      *(bf16x4*)&XCL[c * NSTP + xn4] = l4;
    }
    __syncthreads();

    f32x4 U0 = f32x4{0.f, 0.f, 0.f, 0.f}, U1 = f32x4{0.f, 0.f, 0.f, 0.f};
#pragma unroll
    for (int k = 0; k < 4; ++k) {
      {
        const int o = l15 * XST + k * 32 + q * 8;
        bf16x8 bh = *(const bf16x8*)&XH[o];
        bf16x8 bl = *(const bf16x8*)&XL[o];
        U0 = MFMA16(bh, aWh[k], U0);
        U0 = MFMA16(bl, aWh[k], U0);
        U0 = MFMA16(bh, aWl[k], U0);
      }
      {
        const int o = (16 + l15) * XST + k * 32 + q * 8;
        bf16x8 bh = *(const bf16x8*)&XH[o];
        bf16x8 bl = *(const bf16x8*)&XL[o];
        U1 = MFMA16(bh, aWh[k], U1);
        U1 = MFMA16(bl, aWh[k], U1);
        U1 = MFMA16(bh, aWl[k], U1);
      }
    }

    f32x4 pe0, pe1;
#pragma unroll
    for (int r = 0; r < 4; ++r) {
      pe0[r] = __expf(U0[r]);
      pe1[r] = __expf(U1[r]);
      lsum += pe0[r] + pe1[r];
    }

    const int slo = l15 + ((lane & 16) ? 32 : 0);
    float pj[8];
#pragma unroll
    for (int r = 0; r < 4; ++r) {
      float a0 = __shfl(pe0[r], slo);
      float a1 = __shfl(pe1[r], slo);
      pj[r] = (q & 2) ? a1 : a0;
      float b0 = __shfl(pe0[r], slo + 16);
      float b1 = __shfl(pe1[r], slo + 16);
      pj[4 + r] = (q & 2) ? b1 : b0;
    }
    bf16x8 aPh, aPl;
#pragma unroll
    for (int j = 0; j < 8; ++j) {
      bf16_t hh = (bf16_t)pj[j];
      aPh[j] = hh;
      aPl[j] = (bf16_t)(pj[j] - (float)hh);
    }

#pragma unroll
    for (int cs = 0; cs < 8; ++cs) {
      const int ob = (cs * 16 + l15) * NSTP + q * 8;
      bf16x8 bh = *(const bf16x8*)&XCH[ob];
      bf16x8 bl = *(const bf16x8*)&XCL[ob];
      acc[cs] = MFMA16(aPh, bh, acc[cs]);
      acc[cs] = MFMA16(aPh, bl, acc[cs]);
      acc[cs] = MFMA16(aPl, bh, acc[cs]);
    }
  }

  const size_t sb = (size_t)seg * 32 + b;
  lsum += __shfl_xor(lsum, 16);
  lsum += __shfl_xor(lsum, 32);
  if (lane < 16) ml[sb * 512 + m0 + w * 16 + lane] = lsum;
#pragma unroll
  for (int cs = 0; cs < 8; ++cs)
#pragma unroll
    for (int r = 0; r < 4; ++r) {
      const int m = m0 + w * 16 + q * 4 + r;
      h_part[(sb * 512 + m) * 128 + cs * 16 + l15] = acc[cs][r];
    }
}

// ---------------------------------------------------------------------------
// Combine 4 n-segments.
// ---------------------------------------------------------------------------
__global__ __launch_bounds__(128) void k_combine(const float* __restrict__ h_part,
                                                 const float* __restrict__ ml,
                                                 float* __restrict__ hbuf) {
  const int mb = blockIdx.x;
  const int m = mb >> 5, b = mb & 31;
  const int c = threadIdx.x;
  float L = 0.f, acc = 0.f;
#pragma unroll
  for (int s = 0; s < 4; ++s) {
    L += ml[((size_t)s * 32 + b) * 512 + m];
    acc += h_part[(((size_t)s * 32 + b) * 512 + m) * 128 + c];
  }
  hbuf[(size_t)m * 4096 + b * 128 + c] = acc / L;
}

// ---------------------------------------------------------------------------
// h [512m][4096bc] fp32 -> hT blocked hi/lo:
//   addr = ((b*16 + m/32)*128 + c)*32 + m%32
// ---------------------------------------------------------------------------
__global__ __launch_bounds__(256) void k_hsplit(const float* __restrict__ h,
                                                bf16_t* __restrict__ thi,
                                                bf16_t* __restrict__ tlo) {
  __shared__ float T[64 * 65];  // [c][m]
  const int m0 = blockIdx.x * 64, c0 = blockIdx.y * 64;
  const int t = threadIdx.x;
#pragma unroll
  for (int ii = 0; ii < 4; ++ii) {
    int slot = ii * 256 + t;
    int m = slot >> 4, c4 = (slot & 15) * 4;
    f32x4 v = *(const f32x4*)&h[(size_t)(m0 + m) * 4096 + c0 + c4];
#pragma unroll
    for (int k = 0; k < 4; ++k) T[(c4 + k) * 65 + m] = v[k];
  }
  __syncthreads();
  const int row = t >> 2, mg = (t & 3) * 16;
  const int bc = c0 + row, bb = bc >> 7, cc = bc & 127;
#pragma unroll
  for (int half = 0; half < 2; ++half) {
    bf16x8 h8, l8;
#pragma unroll
    for (int j = 0; j < 8; ++j) {
      float v = T[row * 65 + mg + half * 8 + j];
      bf16_t hh = (bf16_t)v;
      h8[j] = hh;
      l8[j] = (bf16_t)(v - (float)hh);
    }
    const int m8 = m0 + mg + half * 8;
    const size_t ad = (((size_t)bb * 16 + (m8 >> 5)) * 128 + cc) * 32 + (m8 & 31);
    *(bf16x8*)&thi[ad] = h8;
    *(bf16x8*)&tlo[ad] = l8;
  }
}

// ---------------------------------------------------------------------------
// Fused BN + residual + relu + transpose-split -> blocked hT layout.
// ---------------------------------------------------------------------------
__global__ __launch_bounds__(256) void k_bnsplit(const float* __restrict__ ybuf,
                                                 float* __restrict__ hbuf,
                                                 const float* __restrict__ stats,
                                                 const float* __restrict__ gamma,
                                                 const float* __restrict__ beta,
                                                 int l,
                                                 bf16_t* __restrict__ thi,
                                                 bf16_t* __restrict__ tlo) {
  __shared__ float T[64 * 65];  // [c][m]
  const int m0 = blockIdx.x * 64, c0 = blockIdx.y * 64;
  const int t = threadIdx.x;
#pragma unroll
  for (int ii = 0; ii < 4; ++ii) {
    int slot = ii * 256 + t;
    int m = slot >> 4, c4 = (slot & 15) * 4;
    const int o = m0 + m;
    const float mu = stats[l * 1024 + o] * (1.f / 4096.f);
    const float var = stats[l * 1024 + 512 + o] * (1.f / 4096.f) - mu * mu;
    const float rs = rsqrtf(var + 1e-5f);
    const float g = gamma[l * 512 + o];
    const float bt = beta[l * 512 + o];
    const size_t gidx = (size_t)o * 4096 + c0 + c4;
    f32x4 y = *(const f32x4*)&ybuf[gidx];
    f32x4 h = *(const f32x4*)&hbuf[gidx];
    f32x4 r;
#pragma unroll
    for (int k = 0; k < 4; ++k) {
      r[k] = fmaxf((y[k] - mu) * rs * g + bt + h[k], 0.f);
      T[(c4 + k) * 65 + m] = r[k];
    }
    *(f32x4*)&hbuf[gidx] = r;
  }
  __syncthreads();
  const int row = t >> 2, mg = (t & 3) * 16;
  const int bc = c0 + row, bb = bc >> 7, cc = bc & 127;
#pragma unroll
  for (int half = 0; half < 2; ++half) {
    bf16x8 h8, l8;
#pragma unroll
    for (int j = 0; j < 8; ++j) {
      float v = T[row * 65 + mg + half * 8 + j];
      bf16_t hh = (bf16_t)v;
      h8[j] = hh;
      l8[j] = (bf16_t)(v - (float)hh);
    }
    const int m8 = m0 + mg + half * 8;
    const size_t ad = (((size_t)bb * 16 + (m8 >> 5)) * 128 + cc) * 32 + (m8 & 31);
    *(bf16x8*)&thi[ad] = h8;
    *(bf16x8*)&tlo[ad] = l8;
  }
}

// ---------------------------------------------------------------------------
// Layer GEMM — blocked layouts: Wf A-frags and hT B-frags both read as
// contiguous 1KB per wave instruction (were 16 cache lines each).
// ---------------------------------------------------------------------------
__global__ __launch_bounds__(256) void k_layerA(const bf16_t* __restrict__ Whi,
                                                const bf16_t* __restrict__ Wlo,
                                                const bf16_t* __restrict__ hThi,
                                                const bf16_t* __restrict__ hTlo,
                                                int l, float* __restrict__ ybuf,
                                                float* __restrict__ stats) {
  const int o0 = blockIdx.x * 32;
  const int bb = blockIdx.y;   // batch (bc0 = bb*128)
  const int t = threadIdx.x;
  const int w = t >> 6, lane = t & 63, l15 = lane & 15, q = lane >> 4;
  const int bcw = bb * 128 + w * 32;

  f32x4 acc[2][2];
#pragma unroll
  for (int i = 0; i < 2; ++i)
#pragma unroll
    for (int j = 0; j < 2; ++j) acc[i][j] = f32x4{0.f, 0.f, 0.f, 0.f};

  for (int k0 = 0; k0 < M_; k0 += 32) {
    const int mb = k0 >> 5;
    bf16x8 ah[2], al[2], bh[2], bl[2];
#pragma unroll
    for (int os = 0; os < 2; ++os) {
      const size_t ro =
          (((size_t)l * 16 + mb) * 512 + o0 + os * 16 + l15) * 32 + q * 8;
      ah[os] = *(const bf16x8*)&Whi[ro];
      al[os] = *(const bf16x8*)&Wlo[ro];
    }
#pragma unroll
    for (int ns = 0; ns < 2; ++ns) {
      const size_t rb =
          (((size_t)bb * 16 + mb) * 128 + w * 32 + ns * 16 + l15) * 32 + q * 8;
      bh[ns] = *(const bf16x8*)&hThi[rb];
      bl[ns] = *(const bf16x8*)&hTlo[rb];
    }
#pragma unroll
    for (int os = 0; os < 2; ++os)
#pragma unroll
      for (int ns = 0; ns < 2; ++ns) {
        acc[os][ns] = MFMA16(ah[os], bh[ns], acc[os][ns]);
        acc[os][ns] = MFMA16(ah[os], bl[ns], acc[os][ns]);
        acc[os][ns] = MFMA16(al[os], bh[ns], acc[os][ns]);
      }
  }

  float s1[2][4], s2[2][4];
#pragma unroll
  for (int os = 0; os < 2; ++os)
#pragma unroll
    for (int r = 0; r < 4; ++r) {
      float a = 0.f, b2 = 0.f;
#pragma unroll
      for (int ns = 0; ns < 2; ++ns) {
        float v = acc[os][ns][r];
        ybuf[(size_t)(o0 + os * 16 + q * 4 + r) * 4096 + bcw + ns * 16 + l15] = v;
        a += v;
        b2 += v * v;
      }
      s1[os][r] = a;
      s2[os][r] = b2;
    }
#pragma unroll
  for (int os = 0; os < 2; ++os)
#pragma unroll
    for (int r = 0; r < 4; ++r) {
#pragma unroll
      for (int off = 1; off < 16; off <<= 1) {
        s1[os][r] += __shfl_xor(s1[os][r], off);
        s2[os][r] += __shfl_xor(s2[os][r], off);
      }
      if (l15 == 0) {
        const int o = o0 + os * 16 + q * 4 + r;
        atomicAdd(&stats[l * 1024 + o], s1[os][r]);
        atomicAdd(&stats[l * 1024 + 512 + o], s2[os][r]);
      }
    }
}

// ---------------------------------------------------------------------------
// Unpool v4 structure (measured 183us) with blocked Wu + blocked x1 reads
// (were 16 cache lines/instr; now contiguous 1KB/instr).
// ---------------------------------------------------------------------------
__global__ __launch_bounds__(256) void k_unpool(const bf16_t* __restrict__ xsThi,
                                                const bf16_t* __restrict__ xsTlo,
                                                const bf16_t* __restrict__ Wuh,
                                                const bf16_t* __restrict__ Wul,
                                                const float* __restrict__ bun,
                                                const bf16_t* __restrict__ x1hi,
                                                const bf16_t* __restrict__ x1lo,
                                                float* __restrict__ out) {
  __shared__ bf16_t XH[64 * XST], XL[64 * XST];
  __shared__ bf16_t PH[64 * PSTU], PL[64 * PSTU];
  __shared__ float colsum_s[4][64];
  __shared__ float L_s[64];
  const int n0 = blockIdx.x * 64, b = blockIdx.y;
  const int t = threadIdx.x, w = t >> 6, lane = t & 63, l15 = lane & 15, q = lane >> 4;

#pragma unroll
  for (int i = 0; i < 4; ++i) {
    int slot = i * 256 + t;
    int n = slot >> 4, cg = (slot & 15) * 8;
    const size_t g = ((size_t)b * N_ + n0 + n) * C_ + cg;
    *(bf16x8*)&XH[n * XST + cg] = *(const bf16x8*)&xsThi[g];
    *(bf16x8*)&XL[n * XST + cg] = *(const bf16x8*)&xsTlo[g];
  }
  colsum_s[w][lane] = 0.f;
  f32x4 acc[2][4];
#pragma unroll
  for (int cs = 0; cs < 2; ++cs)
#pragma unroll
    for (int nt = 0; nt < 4; ++nt) acc[cs][nt] = f32x4{0.f, 0.f, 0.f, 0.f};
  __syncthreads();

  for (int ch = 0; ch < 8; ++ch) {
    const int mg0 = ch * 64 + w * 16;
    f32x4 U[4];
#pragma unroll
    for (int nt = 0; nt < 4; ++nt) U[nt] = f32x4{0.f, 0.f, 0.f, 0.f};
#pragma unroll
    for (int k = 0; k < 4; ++k) {
      // blocked Wu: addr = (k*512 + m)*32 + q*8, m = mg0 + l15
      const size_t ra = ((size_t)k * 512 + mg0 + l15) * 32 + q * 8;
      bf16x8 ah = *(const bf16x8*)&Wuh[ra];
      bf16x8 al = *(const bf16x8*)&Wul[ra];
#pragma unroll
      for (int nt = 0; nt < 4; ++nt) {
        const int o = (nt * 16 + l15) * XST + k * 32 + q * 8;
        bf16x8 bh = *(const bf16x8*)&XH[o];
        bf16x8 bl = *(const bf16x8*)&XL[o];
        U[nt] = MFMA16(ah, bh, U[nt]);
        U[nt] = MFMA16(ah, bl, U[nt]);
        U[nt] = MFMA16(al, bh, U[nt]);
      }
    }
    float bi[4];
#pragma unroll
    for (int r = 0; r < 4; ++r) bi[r] = bun[mg0 + q * 4 + r];

#pragma unroll
    for (int nt = 0; nt < 4; ++nt) {
      bf16x4 ph4, pl4;
      float s = 0.f;
#pragma unroll
      for (int r = 0; r < 4; ++r) {
        float pv = __expf(U[nt][r] + bi[r]);
        s += pv;
        bf16_t hh = (bf16_t)pv;
        ph4[r] = hh;
        pl4[r] = (bf16_t)(pv - (float)hh);
      }
      s += __shfl_xor(s, 16);
      s += __shfl_xor(s, 32);
      if (lane < 16) colsum_s[w][nt * 16 + lane] += s;
      const int o = (nt * 16 + l15) * PSTU + w * 16 + q * 4;
      *(bf16x4*)&PH[o] = ph4;
      *(bf16x4*)&PL[o] = pl4;
    }
    __syncthreads();  // P complete for all waves

#pragma unroll
    for (int ks = 0; ks < 2; ++ks) {
      bf16x8 ah2[2], al2[2];
#pragma unroll
      for (int cs = 0; cs < 2; ++cs) {
        // blocked x1: addr = ((b*16 + ch*2+ks)*128 + c)*32 + q*8
        const size_t ga =
            (((size_t)b * 16 + ch * 2 + ks) * 128 + w * 32 + cs * 16 + l15) * 32 +
            q * 8;
        ah2[cs] = *(const bf16x8*)&x1hi[ga];
        al2[cs] = *(const bf16x8*)&x1lo[ga];
      }
#pragma unroll
      for (int nt = 0; nt < 4; ++nt) {
        const int o = (nt * 16 + l15) * PSTU + ks * 32 + q * 8;
        bf16x8 bh = *(const bf16x8*)&PH[o];
        bf16x8 bl = *(const bf16x8*)&PL[o];
#pragma unroll
        for (int cs = 0; cs < 2; ++cs) {
          acc[cs][nt] = MFMA16(ah2[cs], bh, acc[cs][nt]);
          acc[cs][nt] = MFMA16(ah2[cs], bl, acc[cs][nt]);
          acc[cs][nt] = MFMA16(al2[cs], bh, acc[cs][nt]);
        }
      }
    }
    __syncthreads();  // apply done before next chunk overwrites P
  }
  if (t < 64)
    L_s[t] = colsum_s[0][t] + colsum_s[1][t] + colsum_s[2][t] + colsum_s[3][t];
  __syncthreads();
#pragma unroll
  for (int nt = 0; nt < 4; ++nt) {
    const float invL = 1.f / L_s[nt * 16 + l15];
#pragma unroll
    for (int cs = 0; cs < 2; ++cs) {
      const int c = w * 32 + cs * 16 + q * 4;
#pragma unroll
      for (int r = 0; r < 4; ++r)
        out[((size_t)b * 128 + c + r) * (size_t)N_ + n0 + nt * 16 + l15] =
            acc[cs][nt][r] * invL;
    }
  }
}

// ---------------------------------------------------------------------------
extern "C" void kernel_launch(void* const* d_in, const int* in_sizes, int n_in,
                              void* d_out, int out_size, void* d_ws, size_t ws_size,
                              hipStream_t stream) {
  const float* x = (const float*)d_in[0];
  const float* W_pool = (const float*)d_in[1];
  const float* Wf = (const float*)d_in[2];
  const float* gamma = (const float*)d_in[3];
  const float* beta = (const float*)d_in[4];
  const float* W_unpool = (const float*)d_in[5];
  const float* b_unpool = (const float*)d_in[6];
  float* out = (float*)d_out;

  char* ws = (char*)d_ws;
  float* h_part = (float*)ws; ws += (size_t)4 * 32 * 512 * 128 * 4;  // 33.55 MB
  float* ml = (float*)ws;     ws += (size_t)4 * 32 * 512 * 4;        // 0.26 MB
  float* hbuf = (float*)ws;   ws += (size_t)512 * 4096 * 4;          // 8.39 MB
  float* stats = (float*)ws;  ws += NL * 1024 * 4;
  bf16_t* xsThi = (bf16_t*)ws; ws += (size_t)32 * N_ * C_ * 2;       // 33.55 MB
  bf16_t* xsTlo = (bf16_t*)ws; ws += (size_t)32 * N_ * C_ * 2;       // 33.55 MB
  bf16_t* Wuh = (bf16_t*)ws;  ws += (size_t)M_ * C_ * 2;
  bf16_t* Wul = (bf16_t*)ws;  ws += (size_t)M_ * C_ * 2;
  bf16_t* Wph = (bf16_t*)ws;  ws += (size_t)M_ * C_ * 2;
  bf16_t* Wpl = (bf16_t*)ws;  ws += (size_t)M_ * C_ * 2;
  bf16_t* Whi = (bf16_t*)ws;  ws += (size_t)NL * M_ * M_ * 2;        // 3.15 MB
  bf16_t* Wlo = (bf16_t*)ws;  ws += (size_t)NL * M_ * M_ * 2;        // 3.15 MB
  // aliased into h_part (dead after k_combine):
  char* hp = (char*)h_part;
  float* ybuf = (float*)(hp);                  // 8.39 MB
  bf16_t* hThi = (bf16_t*)(hp + 8388608);      // 4.19 MB
  bf16_t* hTlo = (bf16_t*)(hp + 12582912);     // 4.19 MB

  hipMemsetAsync(stats, 0, NL * 1024 * 4, stream);
  k_xsplit<<<dim3(64, 32), 256, 0, stream>>>(x, xsThi, xsTlo);
  k_wsplit<<<dim3(64), 256, 0, stream>>>(W_pool, Wph, Wpl);
  k_wusplit<<<dim3(64), 256, 0, stream>>>(W_unpool, Wuh, Wul);
  k_wfsplit<<<dim3(1536), 256, 0, stream>>>(Wf, Whi, Wlo);
  k_pool<<<dim3(1024), 256, 0, stream>>>(xsThi, xsTlo, x, Wph, Wpl,
                                         h_part, ml);
  k_combine<<<dim3(16384), 128, 0, stream>>>(h_part, ml, hbuf);
  k_hsplit<<<dim3(8, 64), 256, 0, stream>>>(hbuf, hThi, hTlo);
  for (int l = 0; l < NL; ++l) {
    k_layerA<<<dim3(16, 32), 256, 0, stream>>>(Whi, Wlo, hThi, hTlo, l, ybuf, stats);
    k_bnsplit<<<dim3(8, 64), 256, 0, stream>>>(ybuf, hbuf, stats, gamma, beta, l,
                                               hThi, hTlo);
  }
  k_unpool<<<dim3(64, 32), 256, 0, stream>>>(xsThi, xsTlo, Wuh, Wul, b_unpool,
                                             hThi, hTlo, out);
}

// Round 15
// 663.870 us; speedup vs baseline: 1.6223x; 1.0548x over previous
//
#include <hip/hip_runtime.h>
#include <hip/hip_bf16.h>

typedef float f32x4 __attribute__((ext_vector_type(4)));
typedef __bf16 bf16_t;
typedef __bf16 bf16x4 __attribute__((ext_vector_type(4)));
typedef __bf16 bf16x8 __attribute__((ext_vector_type(8)));

#define MFMA16(a, b, c) __builtin_amdgcn_mfma_f32_16x16x32_bf16(a, b, c, 0, 0, 0)

constexpr int C_ = 128;
constexpr int N_ = 4096;
constexpr int M_ = 512;
constexpr int NL = 6;

#define NEG_INF (-__builtin_huge_valf())

constexpr int XST = 136;   // xsT tile row stride (bf16), 68 words ≡ 4 mod 32
constexpr int NSTP = 40;   // pool xs [c][n] apply tile row stride (bf16)
constexpr int PSTU = 72;   // unpool P row stride (bf16)

// ---------------------------------------------------------------------------
// Split fp32 array -> hi/lo bf16 (same layout).  (W_pool only)
// ---------------------------------------------------------------------------
__global__ __launch_bounds__(256) void k_wsplit(const float* __restrict__ W,
                                                bf16_t* __restrict__ hi,
                                                bf16_t* __restrict__ lo) {
  const size_t i4 = ((size_t)blockIdx.x * 256 + threadIdx.x) * 4;
  f32x4 v = *(const f32x4*)&W[i4];
  bf16x4 h4, l4;
#pragma unroll
  for (int k = 0; k < 4; ++k) {
    bf16_t h = (bf16_t)v[k];
    h4[k] = h;
    l4[k] = (bf16_t)(v[k] - (float)h);
  }
  *(bf16x4*)&hi[i4] = h4;
  *(bf16x4*)&lo[i4] = l4;
}

// ---------------------------------------------------------------------------
// Wf [l][o][m] fp32 -> blocked: addr = ((l*16 + m/32)*512 + o)*32 + m%32
// ---------------------------------------------------------------------------
__global__ __launch_bounds__(256) void k_wfsplit(const float* __restrict__ W,
                                                 bf16_t* __restrict__ hi,
                                                 bf16_t* __restrict__ lo) {
  const size_t i4 = ((size_t)blockIdx.x * 256 + threadIdx.x) * 4;
  const int l = (int)(i4 >> 18);
  const int rem = (int)(i4 & 262143);
  const int o = rem >> 9, m = rem & 511;
  f32x4 v = *(const f32x4*)&W[i4];
  bf16x4 h4, l4;
#pragma unroll
  for (int k = 0; k < 4; ++k) {
    bf16_t h = (bf16_t)v[k];
    h4[k] = h;
    l4[k] = (bf16_t)(v[k] - (float)h);
  }
  const size_t ad = (((size_t)l * 16 + (m >> 5)) * 512 + o) * 32 + (m & 31);
  *(bf16x4*)&hi[ad] = h4;
  *(bf16x4*)&lo[ad] = l4;
}

// ---------------------------------------------------------------------------
// Wu [m][c] fp32 -> blocked: addr = ((c/32)*512 + m)*32 + c%32
// ---------------------------------------------------------------------------
__global__ __launch_bounds__(256) void k_wusplit(const float* __restrict__ W,
                                                 bf16_t* __restrict__ hi,
                                                 bf16_t* __restrict__ lo) {
  const size_t i4 = ((size_t)blockIdx.x * 256 + threadIdx.x) * 4;
  const int m = (int)(i4 >> 7), c = (int)(i4 & 127);
  f32x4 v = *(const f32x4*)&W[i4];
  bf16x4 h4, l4;
#pragma unroll
  for (int k = 0; k < 4; ++k) {
    bf16_t h = (bf16_t)v[k];
    h4[k] = h;
    l4[k] = (bf16_t)(v[k] - (float)h);
  }
  const size_t ad = ((size_t)(c >> 5) * 512 + m) * 32 + (c & 31);
  *(bf16x4*)&hi[ad] = h4;
  *(bf16x4*)&lo[ad] = l4;
}

// ---------------------------------------------------------------------------
// xs [b][c][n] fp32 -> xsThi/xsTlo [b][n][c] bf16 (transpose + split).
// ---------------------------------------------------------------------------
__global__ __launch_bounds__(256) void k_xsplit(const float* __restrict__ xs,
                                                bf16_t* __restrict__ thi,
                                                bf16_t* __restrict__ tlo) {
  __shared__ float T[128 * 68];  // [c][n]
  const int n0 = blockIdx.x * 64, b = blockIdx.y;
  const int t = threadIdx.x;
  const float* xsb = xs + (size_t)b * C_ * N_;
#pragma unroll
  for (int i = 0; i < 8; ++i) {
    int slot = i * 256 + t;  // 0..2047
    int c = slot >> 4, n4 = (slot & 15) * 4;
    *(f32x4*)&T[c * 68 + n4] = *(const f32x4*)&xsb[(size_t)c * N_ + n0 + n4];
  }
  __syncthreads();
  const int n = t >> 2, cb = (t & 3) * 32;
  bf16x8 h8[4], l8[4];
#pragma unroll
  for (int g = 0; g < 4; ++g)
#pragma unroll
    for (int j = 0; j < 8; ++j) {
      float v = T[(cb + g * 8 + j) * 68 + n];
      bf16_t hh = (bf16_t)v;
      h8[g][j] = hh;
      l8[g][j] = (bf16_t)(v - (float)hh);
    }
  const size_t base = ((size_t)b * N_ + n0 + n) * C_ + cb;
#pragma unroll
  for (int g = 0; g < 4; ++g) {
    *(bf16x8*)&thi[base + g * 8] = h8[g];
    *(bf16x8*)&tlo[base + g * 8] = l8[g];
  }
}

// ---------------------------------------------------------------------------
// Pool v12: single-barrier double-buffered staging.
// Per chunk: barrier -> issue stage loads(ch+1) -> compute(buf p) -> write
// staged regs into buf p^1.  Loads drain at the ds_write AFTER compute (a
// full compute phase of latency hiding); barrier count halves (64 -> 32).
// XC stage writes bf16x8 (16B) - v11's bf16x4 writes were ~4-way bank
// conflicted (25.2M).  LDS 75.8 KB -> 2 blocks/CU (matches measured
// effective occupancy; stalls removed instead).
// ---------------------------------------------------------------------------
__global__ __launch_bounds__(256) void k_pool(const bf16_t* __restrict__ xsThi,
                                              const bf16_t* __restrict__ xsTlo,
                                              const float* __restrict__ x,
                                              const bf16_t* __restrict__ Wph,
                                              const bf16_t* __restrict__ Wpl,
                                              float* __restrict__ h_part,
                                              float* __restrict__ ml) {
  __shared__ bf16_t XH2[2][32 * XST], XL2[2][32 * XST];
  __shared__ bf16_t XCH2[2][128 * NSTP], XCL2[2][128 * NSTP];
  const int d = blockIdx.x;
  const int lin = ((d & 7) << 7) | (d >> 3);
  const int b = lin >> 5, r5 = lin & 31;
  const int mt = r5 >> 2, seg = r5 & 3;
  const int m0 = mt * 64;
  const int t = threadIdx.x, w = t >> 6, lane = t & 63, l15 = lane & 15, q = lane >> 4;

  const int sn0 = t >> 4, sn1 = (256 + t) >> 4;
  const int scg = (t & 15) * 8;
  const size_t sgb = ((size_t)b * N_ + seg * 1024) * C_ + scg;
  const int xc2 = t >> 2, xn8 = (t & 3) * 8;  // XC stage: 2 c-rows, 8 n each
  const float* xb = x + (size_t)b * C_ * N_;

  bf16x8 aWh[4], aWl[4];
#pragma unroll
  for (int k = 0; k < 4; ++k) {
    const size_t ra = (size_t)(m0 + w * 16 + l15) * C_ + k * 32 + q * 8;
    aWh[k] = *(const bf16x8*)&Wph[ra];
    aWl[k] = *(const bf16x8*)&Wpl[ra];
  }

  f32x4 acc[8];
#pragma unroll
  for (int cs = 0; cs < 8; ++cs) acc[cs] = f32x4{0.f, 0.f, 0.f, 0.f};
  float lsum = 0.f;

  // staged regs
  bf16x8 th0, th1, tl0, tl1;
  float xf[2][8];

  // ---- prologue: load + write chunk 0 into buf 0 ----
  {
    const size_t off = sgb;
    th0 = *(const bf16x8*)&xsThi[off + (size_t)sn0 * C_];
    th1 = *(const bf16x8*)&xsThi[off + (size_t)sn1 * C_];
    tl0 = *(const bf16x8*)&xsTlo[off + (size_t)sn0 * C_];
    tl1 = *(const bf16x8*)&xsTlo[off + (size_t)sn1 * C_];
#pragma unroll
    for (int i = 0; i < 2; ++i) {
      const int c = xc2 + i * 64;
      *(f32x4*)&xf[i][0] = *(const f32x4*)&xb[(size_t)c * N_ + seg * 1024 + xn8];
      *(f32x4*)&xf[i][4] = *(const f32x4*)&xb[(size_t)c * N_ + seg * 1024 + xn8 + 4];
    }
    *(bf16x8*)&XH2[0][sn0 * XST + scg] = th0;
    *(bf16x8*)&XH2[0][sn1 * XST + scg] = th1;
    *(bf16x8*)&XL2[0][sn0 * XST + scg] = tl0;
    *(bf16x8*)&XL2[0][sn1 * XST + scg] = tl1;
#pragma unroll
    for (int i = 0; i < 2; ++i) {
      const int c = xc2 + i * 64;
      bf16x8 h8, l8;
#pragma unroll
      for (int j = 0; j < 8; ++j) {
        bf16_t hh = (bf16_t)xf[i][j];
        h8[j] = hh;
        l8[j] = (bf16_t)(xf[i][j] - (float)hh);
      }
      *(bf16x8*)&XCH2[0][c * NSTP + xn8] = h8;
      *(bf16x8*)&XCL2[0][c * NSTP + xn8] = l8;
    }
  }

  int p = 0;
  for (int ch = 0; ch < 32; ++ch) {
    __syncthreads();  // buf[p] ready

    // ---- issue stage loads for ch+1 (consumed after compute) ----
    if (ch < 31) {
      const int nn = seg * 1024 + (ch + 1) * 32;
      const size_t off = sgb + (size_t)(ch + 1) * 32 * C_;
      th0 = *(const bf16x8*)&xsThi[off + (size_t)sn0 * C_];
      th1 = *(const bf16x8*)&xsThi[off + (size_t)sn1 * C_];
      tl0 = *(const bf16x8*)&xsTlo[off + (size_t)sn0 * C_];
      tl1 = *(const bf16x8*)&xsTlo[off + (size_t)sn1 * C_];
#pragma unroll
      for (int i = 0; i < 2; ++i) {
        const int c = xc2 + i * 64;
        *(f32x4*)&xf[i][0] = *(const f32x4*)&xb[(size_t)c * N_ + nn + xn8];
        *(f32x4*)&xf[i][4] = *(const f32x4*)&xb[(size_t)c * N_ + nn + xn8 + 4];
      }
    }

    const bf16_t* XH = &XH2[p][0];
    const bf16_t* XL = &XL2[p][0];
    const bf16_t* XCH = &XCH2[p][0];
    const bf16_t* XCL = &XCL2[p][0];

    // ---- logits U'[32n][16m], swapped operands ----
    f32x4 U0 = f32x4{0.f, 0.f, 0.f, 0.f}, U1 = f32x4{0.f, 0.f, 0.f, 0.f};
#pragma unroll
    for (int k = 0; k < 4; ++k) {
      {
        const int o = l15 * XST + k * 32 + q * 8;
        bf16x8 bh = *(const bf16x8*)&XH[o];
        bf16x8 bl = *(const bf16x8*)&XL[o];
        U0 = MFMA16(bh, aWh[k], U0);
        U0 = MFMA16(bl, aWh[k], U0);
        U0 = MFMA16(bh, aWl[k], U0);
      }
      {
        const int o = (16 + l15) * XST + k * 32 + q * 8;
        bf16x8 bh = *(const bf16x8*)&XH[o];
        bf16x8 bl = *(const bf16x8*)&XL[o];
        U1 = MFMA16(bh, aWh[k], U1);
        U1 = MFMA16(bl, aWh[k], U1);
        U1 = MFMA16(bh, aWl[k], U1);
      }
    }

    f32x4 pe0, pe1;
#pragma unroll
    for (int r = 0; r < 4; ++r) {
      pe0[r] = __expf(U0[r]);
      pe1[r] = __expf(U1[r]);
      lsum += pe0[r] + pe1[r];
    }

    // ---- in-register transpose (v8-verified) ----
    const int slo = l15 + ((lane & 16) ? 32 : 0);
    float pj[8];
#pragma unroll
    for (int r = 0; r < 4; ++r) {
      float a0 = __shfl(pe0[r], slo);
      float a1 = __shfl(pe1[r], slo);
      pj[r] = (q & 2) ? a1 : a0;
      float b0 = __shfl(pe0[r], slo + 16);
      float b1 = __shfl(pe1[r], slo + 16);
      pj[4 + r] = (q & 2) ? b1 : b0;
    }
    bf16x8 aPh, aPl;
#pragma unroll
    for (int j = 0; j < 8; ++j) {
      bf16_t hh = (bf16_t)pj[j];
      aPh[j] = hh;
      aPl[j] = (bf16_t)(pj[j] - (float)hh);
    }

    // ---- apply from LDS ----
#pragma unroll
    for (int cs = 0; cs < 8; ++cs) {
      const int ob = (cs * 16 + l15) * NSTP + q * 8;
      bf16x8 bh = *(const bf16x8*)&XCH[ob];
      bf16x8 bl = *(const bf16x8*)&XCL[ob];
      acc[cs] = MFMA16(aPh, bh, acc[cs]);
      acc[cs] = MFMA16(aPh, bl, acc[cs]);
      acc[cs] = MFMA16(aPl, bh, acc[cs]);
    }

    // ---- write staged regs for ch+1 into the other buffer ----
    if (ch < 31) {
      const int pn = p ^ 1;
      *(bf16x8*)&XH2[pn][sn0 * XST + scg] = th0;
      *(bf16x8*)&XH2[pn][sn1 * XST + scg] = th1;
      *(bf16x8*)&XL2[pn][sn0 * XST + scg] = tl0;
      *(bf16x8*)&XL2[pn][sn1 * XST + scg] = tl1;
#pragma unroll
      for (int i = 0; i < 2; ++i) {
        const int c = xc2 + i * 64;
        bf16x8 h8, l8;
#pragma unroll
        for (int j = 0; j < 8; ++j) {
          bf16_t hh = (bf16_t)xf[i][j];
          h8[j] = hh;
          l8[j] = (bf16_t)(xf[i][j] - (float)hh);
        }
        *(bf16x8*)&XCH2[pn][c * NSTP + xn8] = h8;
        *(bf16x8*)&XCL2[pn][c * NSTP + xn8] = l8;
      }
    }
    p ^= 1;
  }

  const size_t sb = (size_t)seg * 32 + b;
  lsum += __shfl_xor(lsum, 16);
  lsum += __shfl_xor(lsum, 32);
  if (lane < 16) ml[sb * 512 + m0 + w * 16 + lane] = lsum;
#pragma unroll
  for (int cs = 0; cs < 8; ++cs)
#pragma unroll
    for (int r = 0; r < 4; ++r) {
      const int m = m0 + w * 16 + q * 4 + r;
      h_part[(sb * 512 + m) * 128 + cs * 16 + l15] = acc[cs][r];
    }
}

// ---------------------------------------------------------------------------
// Combine 4 n-segments.
// ---------------------------------------------------------------------------
__global__ __launch_bounds__(128) void k_combine(const float* __restrict__ h_part,
                                                 const float* __restrict__ ml,
                                                 float* __restrict__ hbuf) {
  const int mb = blockIdx.x;
  const int m = mb >> 5, b = mb & 31;
  const int c = threadIdx.x;
  float L = 0.f, acc = 0.f;
#pragma unroll
  for (int s = 0; s < 4; ++s) {
    L += ml[((size_t)s * 32 + b) * 512 + m];
    acc += h_part[(((size_t)s * 32 + b) * 512 + m) * 128 + c];
  }
  hbuf[(size_t)m * 4096 + b * 128 + c] = acc / L;
}

// ---------------------------------------------------------------------------
// h [512m][4096bc] fp32 -> hT blocked: ((b*16 + m/32)*128 + c)*32 + m%32
// ---------------------------------------------------------------------------
__global__ __launch_bounds__(256) void k_hsplit(const float* __restrict__ h,
                                                bf16_t* __restrict__ thi,
                                                bf16_t* __restrict__ tlo) {
  __shared__ float T[64 * 65];  // [c][m]
  const int m0 = blockIdx.x * 64, c0 = blockIdx.y * 64;
  const int t = threadIdx.x;
#pragma unroll
  for (int ii = 0; ii < 4; ++ii) {
    int slot = ii * 256 + t;
    int m = slot >> 4, c4 = (slot & 15) * 4;
    f32x4 v = *(const f32x4*)&h[(size_t)(m0 + m) * 4096 + c0 + c4];
#pragma unroll
    for (int k = 0; k < 4; ++k) T[(c4 + k) * 65 + m] = v[k];
  }
  __syncthreads();
  const int row = t >> 2, mg = (t & 3) * 16;
  const int bc = c0 + row, bb = bc >> 7, cc = bc & 127;
#pragma unroll
  for (int half = 0; half < 2; ++half) {
    bf16x8 h8, l8;
#pragma unroll
    for (int j = 0; j < 8; ++j) {
      float v = T[row * 65 + mg + half * 8 + j];
      bf16_t hh = (bf16_t)v;
      h8[j] = hh;
      l8[j] = (bf16_t)(v - (float)hh);
    }
    const int m8 = m0 + mg + half * 8;
    const size_t ad = (((size_t)bb * 16 + (m8 >> 5)) * 128 + cc) * 32 + (m8 & 31);
    *(bf16x8*)&thi[ad] = h8;
    *(bf16x8*)&tlo[ad] = l8;
  }
}

// ---------------------------------------------------------------------------
// Fused BN + residual + relu + transpose-split -> blocked hT layout.
// ---------------------------------------------------------------------------
__global__ __launch_bounds__(256) void k_bnsplit(const float* __restrict__ ybuf,
                                                 float* __restrict__ hbuf,
                                                 const float* __restrict__ stats,
                                                 const float* __restrict__ gamma,
                                                 const float* __restrict__ beta,
                                                 int l,
                                                 bf16_t* __restrict__ thi,
                                                 bf16_t* __restrict__ tlo) {
  __shared__ float T[64 * 65];  // [c][m]
  const int m0 = blockIdx.x * 64, c0 = blockIdx.y * 64;
  const int t = threadIdx.x;
#pragma unroll
  for (int ii = 0; ii < 4; ++ii) {
    int slot = ii * 256 + t;
    int m = slot >> 4, c4 = (slot & 15) * 4;
    const int o = m0 + m;
    const float mu = stats[l * 1024 + o] * (1.f / 4096.f);
    const float var = stats[l * 1024 + 512 + o] * (1.f / 4096.f) - mu * mu;
    const float rs = rsqrtf(var + 1e-5f);
    const float g = gamma[l * 512 + o];
    const float bt = beta[l * 512 + o];
    const size_t gidx = (size_t)o * 4096 + c0 + c4;
    f32x4 y = *(const f32x4*)&ybuf[gidx];
    f32x4 h = *(const f32x4*)&hbuf[gidx];
    f32x4 r;
#pragma unroll
    for (int k = 0; k < 4; ++k) {
      r[k] = fmaxf((y[k] - mu) * rs * g + bt + h[k], 0.f);
      T[(c4 + k) * 65 + m] = r[k];
    }
    *(f32x4*)&hbuf[gidx] = r;
  }
  __syncthreads();
  const int row = t >> 2, mg = (t & 3) * 16;
  const int bc = c0 + row, bb = bc >> 7, cc = bc & 127;
#pragma unroll
  for (int half = 0; half < 2; ++half) {
    bf16x8 h8, l8;
#pragma unroll
    for (int j = 0; j < 8; ++j) {
      float v = T[row * 65 + mg + half * 8 + j];
      bf16_t hh = (bf16_t)v;
      h8[j] = hh;
      l8[j] = (bf16_t)(v - (float)hh);
    }
    const int m8 = m0 + mg + half * 8;
    const size_t ad = (((size_t)bb * 16 + (m8 >> 5)) * 128 + cc) * 32 + (m8 & 31);
    *(bf16x8*)&thi[ad] = h8;
    *(bf16x8*)&tlo[ad] = l8;
  }
}

// ---------------------------------------------------------------------------
// Layer GEMM — blocked layouts (unchanged from v11, measured good).
// ---------------------------------------------------------------------------
__global__ __launch_bounds__(256) void k_layerA(const bf16_t* __restrict__ Whi,
                                                const bf16_t* __restrict__ Wlo,
                                                const bf16_t* __restrict__ hThi,
                                                const bf16_t* __restrict__ hTlo,
                                                int l, float* __restrict__ ybuf,
                                                float* __restrict__ stats) {
  const int o0 = blockIdx.x * 32;
  const int bb = blockIdx.y;
  const int t = threadIdx.x;
  const int w = t >> 6, lane = t & 63, l15 = lane & 15, q = lane >> 4;
  const int bcw = bb * 128 + w * 32;

  f32x4 acc[2][2];
#pragma unroll
  for (int i = 0; i < 2; ++i)
#pragma unroll
    for (int j = 0; j < 2; ++j) acc[i][j] = f32x4{0.f, 0.f, 0.f, 0.f};

  for (int k0 = 0; k0 < M_; k0 += 32) {
    const int mb = k0 >> 5;
    bf16x8 ah[2], al[2], bh[2], bl[2];
#pragma unroll
    for (int os = 0; os < 2; ++os) {
      const size_t ro =
          (((size_t)l * 16 + mb) * 512 + o0 + os * 16 + l15) * 32 + q * 8;
      ah[os] = *(const bf16x8*)&Whi[ro];
      al[os] = *(const bf16x8*)&Wlo[ro];
    }
#pragma unroll
    for (int ns = 0; ns < 2; ++ns) {
      const size_t rb =
          (((size_t)bb * 16 + mb) * 128 + w * 32 + ns * 16 + l15) * 32 + q * 8;
      bh[ns] = *(const bf16x8*)&hThi[rb];
      bl[ns] = *(const bf16x8*)&hTlo[rb];
    }
#pragma unroll
    for (int os = 0; os < 2; ++os)
#pragma unroll
      for (int ns = 0; ns < 2; ++ns) {
        acc[os][ns] = MFMA16(ah[os], bh[ns], acc[os][ns]);
        acc[os][ns] = MFMA16(ah[os], bl[ns], acc[os][ns]);
        acc[os][ns] = MFMA16(al[os], bh[ns], acc[os][ns]);
      }
  }

  float s1[2][4], s2[2][4];
#pragma unroll
  for (int os = 0; os < 2; ++os)
#pragma unroll
    for (int r = 0; r < 4; ++r) {
      float a = 0.f, b2 = 0.f;
#pragma unroll
      for (int ns = 0; ns < 2; ++ns) {
        float v = acc[os][ns][r];
        ybuf[(size_t)(o0 + os * 16 + q * 4 + r) * 4096 + bcw + ns * 16 + l15] = v;
        a += v;
        b2 += v * v;
      }
      s1[os][r] = a;
      s2[os][r] = b2;
    }
#pragma unroll
  for (int os = 0; os < 2; ++os)
#pragma unroll
    for (int r = 0; r < 4; ++r) {
#pragma unroll
      for (int off = 1; off < 16; off <<= 1) {
        s1[os][r] += __shfl_xor(s1[os][r], off);
        s2[os][r] += __shfl_xor(s2[os][r], off);
      }
      if (l15 == 0) {
        const int o = o0 + os * 16 + q * 4 + r;
        atomicAdd(&stats[l * 1024 + o], s1[os][r]);
        atomicAdd(&stats[l * 1024 + 512 + o], s2[os][r]);
      }
    }
}

// ---------------------------------------------------------------------------
// Unpool v6: single-barrier double-buffered P; x1 loads hoisted to chunk top
// (global, independent of LDS -> latency hides under U+exp+P).  Blocked
// Wu/x1 reads (v11).  1 barrier/chunk instead of 2.
// ---------------------------------------------------------------------------
__global__ __launch_bounds__(256) void k_unpool(const bf16_t* __restrict__ xsThi,
                                                const bf16_t* __restrict__ xsTlo,
                                                const bf16_t* __restrict__ Wuh,
                                                const bf16_t* __restrict__ Wul,
                                                const float* __restrict__ bun,
                                                const bf16_t* __restrict__ x1hi,
                                                const bf16_t* __restrict__ x1lo,
                                                float* __restrict__ out) {
  __shared__ bf16_t XH[64 * XST], XL[64 * XST];
  __shared__ bf16_t PH2[2][64 * PSTU], PL2[2][64 * PSTU];
  __shared__ float colsum_s[4][64];
  __shared__ float L_s[64];
  const int n0 = blockIdx.x * 64, b = blockIdx.y;
  const int t = threadIdx.x, w = t >> 6, lane = t & 63, l15 = lane & 15, q = lane >> 4;

#pragma unroll
  for (int i = 0; i < 4; ++i) {
    int slot = i * 256 + t;
    int n = slot >> 4, cg = (slot & 15) * 8;
    const size_t g = ((size_t)b * N_ + n0 + n) * C_ + cg;
    *(bf16x8*)&XH[n * XST + cg] = *(const bf16x8*)&xsThi[g];
    *(bf16x8*)&XL[n * XST + cg] = *(const bf16x8*)&xsTlo[g];
  }
  colsum_s[w][lane] = 0.f;
  f32x4 acc[2][4];
#pragma unroll
  for (int cs = 0; cs < 2; ++cs)
#pragma unroll
    for (int nt = 0; nt < 4; ++nt) acc[cs][nt] = f32x4{0.f, 0.f, 0.f, 0.f};
  __syncthreads();

  int p = 0;
  for (int ch = 0; ch < 8; ++ch) {
    const int mg0 = ch * 64 + w * 16;

    // ---- hoisted x1 A-frag loads (blocked, coalesced; used in apply) ----
    bf16x8 xah[2][2], xal[2][2];
#pragma unroll
    for (int ks = 0; ks < 2; ++ks)
#pragma unroll
      for (int cs = 0; cs < 2; ++cs) {
        const size_t ga =
            (((size_t)b * 16 + ch * 2 + ks) * 128 + w * 32 + cs * 16 + l15) * 32 +
            q * 8;
        xah[ks][cs] = *(const bf16x8*)&x1hi[ga];
        xal[ks][cs] = *(const bf16x8*)&x1lo[ga];
      }

    f32x4 U[4];
#pragma unroll
    for (int nt = 0; nt < 4; ++nt) U[nt] = f32x4{0.f, 0.f, 0.f, 0.f};
#pragma unroll
    for (int k = 0; k < 4; ++k) {
      const size_t ra = ((size_t)k * 512 + mg0 + l15) * 32 + q * 8;
      bf16x8 ah = *(const bf16x8*)&Wuh[ra];
      bf16x8 al = *(const bf16x8*)&Wul[ra];
#pragma unroll
      for (int nt = 0; nt < 4; ++nt) {
        const int o = (nt * 16 + l15) * XST + k * 32 + q * 8;
        bf16x8 bh = *(const bf16x8*)&XH[o];
        bf16x8 bl = *(const bf16x8*)&XL[o];
        U[nt] = MFMA16(ah, bh, U[nt]);
        U[nt] = MFMA16(ah, bl, U[nt]);
        U[nt] = MFMA16(al, bh, U[nt]);
      }
    }
    float bi[4];
#pragma unroll
    for (int r = 0; r < 4; ++r) bi[r] = bun[mg0 + q * 4 + r];

#pragma unroll
    for (int nt = 0; nt < 4; ++nt) {
      bf16x4 ph4, pl4;
      float s = 0.f;
#pragma unroll
      for (int r = 0; r < 4; ++r) {
        float pv = __expf(U[nt][r] + bi[r]);
        s += pv;
        bf16_t hh = (bf16_t)pv;
        ph4[r] = hh;
        pl4[r] = (bf16_t)(pv - (float)hh);
      }
      s += __shfl_xor(s, 16);
      s += __shfl_xor(s, 32);
      if (lane < 16) colsum_s[w][nt * 16 + lane] += s;
      const int o = (nt * 16 + l15) * PSTU + w * 16 + q * 4;
      *(bf16x4*)&PH2[p][o] = ph4;
      *(bf16x4*)&PL2[p][o] = pl4;
    }
    __syncthreads();  // P(ch) visible; prior buffer's readers all done

#pragma unroll
    for (int ks = 0; ks < 2; ++ks) {
#pragma unroll
      for (int nt = 0; nt < 4; ++nt) {
        const int o = (nt * 16 + l15) * PSTU + ks * 32 + q * 8;
        bf16x8 bh = *(const bf16x8*)&PH2[p][o];
        bf16x8 bl = *(const bf16x8*)&PL2[p][o];
#pragma unroll
        for (int cs = 0; cs < 2; ++cs) {
          acc[cs][nt] = MFMA16(xah[ks][cs], bh, acc[cs][nt]);
          acc[cs][nt] = MFMA16(xah[ks][cs], bl, acc[cs][nt]);
          acc[cs][nt] = MFMA16(xal[ks][cs], bh, acc[cs][nt]);
        }
      }
    }
    p ^= 1;
  }
  __syncthreads();  // all colsum_s contributions done
  if (t < 64)
    L_s[t] = colsum_s[0][t] + colsum_s[1][t] + colsum_s[2][t] + colsum_s[3][t];
  __syncthreads();
#pragma unroll
  for (int nt = 0; nt < 4; ++nt) {
    const float invL = 1.f / L_s[nt * 16 + l15];
#pragma unroll
    for (int cs = 0; cs < 2; ++cs) {
      const int c = w * 32 + cs * 16 + q * 4;
#pragma unroll
      for (int r = 0; r < 4; ++r)
        out[((size_t)b * 128 + c + r) * (size_t)N_ + n0 + nt * 16 + l15] =
            acc[cs][nt][r] * invL;
    }
  }
}

// ---------------------------------------------------------------------------
extern "C" void kernel_launch(void* const* d_in, const int* in_sizes, int n_in,
                              void* d_out, int out_size, void* d_ws, size_t ws_size,
                              hipStream_t stream) {
  const float* x = (const float*)d_in[0];
  const float* W_pool = (const float*)d_in[1];
  const float* Wf = (const float*)d_in[2];
  const float* gamma = (const float*)d_in[3];
  const float* beta = (const float*)d_in[4];
  const float* W_unpool = (const float*)d_in[5];
  const float* b_unpool = (const float*)d_in[6];
  float* out = (float*)d_out;

  char* ws = (char*)d_ws;
  float* h_part = (float*)ws; ws += (size_t)4 * 32 * 512 * 128 * 4;  // 33.55 MB
  float* ml = (float*)ws;     ws += (size_t)4 * 32 * 512 * 4;        // 0.26 MB
  float* hbuf = (float*)ws;   ws += (size_t)512 * 4096 * 4;          // 8.39 MB
  float* stats = (float*)ws;  ws += NL * 1024 * 4;
  bf16_t* xsThi = (bf16_t*)ws; ws += (size_t)32 * N_ * C_ * 2;       // 33.55 MB
  bf16_t* xsTlo = (bf16_t*)ws; ws += (size_t)32 * N_ * C_ * 2;       // 33.55 MB
  bf16_t* Wuh = (bf16_t*)ws;  ws += (size_t)M_ * C_ * 2;
  bf16_t* Wul = (bf16_t*)ws;  ws += (size_t)M_ * C_ * 2;
  bf16_t* Wph = (bf16_t*)ws;  ws += (size_t)M_ * C_ * 2;
  bf16_t* Wpl = (bf16_t*)ws;  ws += (size_t)M_ * C_ * 2;
  bf16_t* Whi = (bf16_t*)ws;  ws += (size_t)NL * M_ * M_ * 2;        // 3.15 MB
  bf16_t* Wlo = (bf16_t*)ws;  ws += (size_t)NL * M_ * M_ * 2;        // 3.15 MB
  // aliased into h_part (dead after k_combine):
  char* hp = (char*)h_part;
  float* ybuf = (float*)(hp);                  // 8.39 MB
  bf16_t* hThi = (bf16_t*)(hp + 8388608);      // 4.19 MB
  bf16_t* hTlo = (bf16_t*)(hp + 12582912);     // 4.19 MB

  hipMemsetAsync(stats, 0, NL * 1024 * 4, stream);
  k_xsplit<<<dim3(64, 32), 256, 0, stream>>>(x, xsThi, xsTlo);
  k_wsplit<<<dim3(64), 256, 0, stream>>>(W_pool, Wph, Wpl);
  k_wusplit<<<dim3(64), 256, 0, stream>>>(W_unpool, Wuh, Wul);
  k_wfsplit<<<dim3(1536), 256, 0, stream>>>(Wf, Whi, Wlo);
  k_pool<<<dim3(1024), 256, 0, stream>>>(xsThi, xsTlo, x, Wph, Wpl,
                                         h_part, ml);
  k_combine<<<dim3(16384), 128, 0, stream>>>(h_part, ml, hbuf);
  k_hsplit<<<dim3(8, 64), 256, 0, stream>>>(hbuf, hThi, hTlo);
  for (int l = 0; l < NL; ++l) {
    k_layerA<<<dim3(16, 32), 256, 0, stream>>>(Whi, Wlo, hThi, hTlo, l, ybuf, stats);
    k_bnsplit<<<dim3(8, 64), 256, 0, stream>>>(ybuf, hbuf, stats, gamma, beta, l,
                                               hThi, hTlo);
  }
  k_unpool<<<dim3(64, 32), 256, 0, stream>>>(xsThi, xsTlo, Wuh, Wul, b_unpool,
                                             hThi, hTlo, out);
}